// Round 8
// baseline (314.206 us; speedup 1.0000x reference)
//
#include <hip/hip_runtime.h>
#include <hip/hip_bf16.h>

// Two-layer RGCN (mean aggregation per relation) for MI355X.
// Round 8: fused aggregate+GEMM made latency-tolerant:
//  - double-buffered B tile in LDS, ONE barrier per segment
//  - A-fragment gather for segment s+1 issued before MFMAs of segment s
//  - Bt row stride 272 B (17x16B) -> 4 lanes/bank-quad, no XOR swizzle
//  - CSR segment id = dst*8 + et (node-major): per-row boundaries coalesced
// CSR build / converts otherwise unchanged from round 7 (258.8 us).

#define D_IN 128
#define NREL 8
#define BTSTRIDE 136  // ushorts per padded B row (136*2 = 272 B = 17*16B)

typedef short bf16x8 __attribute__((ext_vector_type(8)));
typedef float f32x4 __attribute__((ext_vector_type(4)));

__device__ __forceinline__ ushort cvbf(float f) {  // f32 -> bf16 RNE
    unsigned u = __float_as_uint(f);
    return (ushort)((u + 0x7FFFu + ((u >> 16) & 1u)) >> 16);
}
__device__ __forceinline__ float bflo(unsigned v) { return __uint_as_float(v << 16); }
__device__ __forceinline__ float bfhi(unsigned v) { return __uint_as_float(v & 0xFFFF0000u); }

// ---------------- f32 -> bf16 convert (4 elems/thread) ----------------
__global__ void to_bf16_kernel(const float* __restrict__ in,
                               ushort* __restrict__ out, int n4) {
    int i = blockIdx.x * blockDim.x + threadIdx.x;
    if (i >= n4) return;
    float4 v = ((const float4*)in)[i];
    ushort4 o;
    o.x = cvbf(v.x); o.y = cvbf(v.y); o.z = cvbf(v.z); o.w = cvbf(v.w);
    ((ushort4*)out)[i] = o;
}

// -------- weight pre-transform: bf16, transposed, padded row stride --------
// Wt[s][n][k] at ((s*NCOLS + n)*BTSTRIDE + k); k in [0,128), pad unwritten.
__global__ void wt_transform_kernel(const float* __restrict__ W,
                                    const float* __restrict__ root,
                                    ushort* __restrict__ Wt, int NCOLS) {
    int i = blockIdx.x * blockDim.x + threadIdx.x;
    int tot = (NREL + 1) * D_IN * NCOLS;
    if (i >= tot) return;
    int s = i / (D_IN * NCOLS);
    int r = i - s * D_IN * NCOLS;
    int k = r / NCOLS;
    int n = r - k * NCOLS;
    float v = (s < NREL) ? W[(size_t)s * D_IN * NCOLS + (size_t)k * NCOLS + n]
                         : root[(size_t)k * NCOLS + n];
    Wt[((size_t)s * NCOLS + n) * BTSTRIDE + k] = cvbf(v);
}

// ---------------- CSR build (seg = dst*8 + et, node-major) ----------------
__global__ void count_kernel(const int* __restrict__ dst,
                             const int* __restrict__ et,
                             int* __restrict__ cnt, int E, int N) {
    int e = blockIdx.x * blockDim.x + threadIdx.x;
    if (e < E) atomicAdd(&cnt[dst[e] * NREL + et[e]], 1);
}

__global__ void scan_block_sum(const int* __restrict__ cnt,
                               int* __restrict__ bsum, int nseg) {
    __shared__ int s[256];
    int base = blockIdx.x * 1024 + threadIdx.x * 4;
    int v = 0;
#pragma unroll
    for (int i = 0; i < 4; ++i) {
        int idx = base + i;
        if (idx < nseg) v += cnt[idx];
    }
    s[threadIdx.x] = v;
    __syncthreads();
    for (int off = 128; off > 0; off >>= 1) {
        if (threadIdx.x < off) s[threadIdx.x] += s[threadIdx.x + off];
        __syncthreads();
    }
    if (threadIdx.x == 0) bsum[blockIdx.x] = s[0];
}

__global__ void scan_bsum(int* __restrict__ bsum, int nb) {
    __shared__ int s[512];
    int t = threadIdx.x;
    int my = (t < nb) ? bsum[t] : 0;
    s[t] = my;
    __syncthreads();
    for (int off = 1; off < 512; off <<= 1) {
        int v = (t >= off) ? s[t - off] : 0;
        __syncthreads();
        s[t] += v;
        __syncthreads();
    }
    if (t < nb) bsum[t] = s[t] - my;  // exclusive
}

__global__ void scan_write(const int* __restrict__ cnt,
                           const int* __restrict__ bsum,
                           int* __restrict__ off, int nseg) {
    __shared__ int s[256];
    int t = threadIdx.x;
    int base = blockIdx.x * 1024 + t * 4;
    int v[4];
    int sum = 0;
#pragma unroll
    for (int i = 0; i < 4; ++i) {
        int idx = base + i;
        v[i] = (idx < nseg) ? cnt[idx] : 0;
        sum += v[i];
    }
    s[t] = sum;
    __syncthreads();
    int my = sum;
    for (int o = 1; o < 256; o <<= 1) {
        int x = (t >= o) ? s[t - o] : 0;
        __syncthreads();
        s[t] += x;
        __syncthreads();
    }
    int pre = s[t] - my + bsum[blockIdx.x];
#pragma unroll
    for (int i = 0; i < 4; ++i) {
        int idx = base + i;
        if (idx < nseg) {
            off[idx] = pre;
            pre += v[i];
        }
    }
}

__global__ void bucket_kernel(const int* __restrict__ src,
                              const int* __restrict__ dst,
                              const int* __restrict__ et,
                              int* __restrict__ off,
                              int* __restrict__ sids, int E, int N) {
    int e = blockIdx.x * blockDim.x + threadIdx.x;
    if (e < E) {
        int seg = dst[e] * NREL + et[e];
        int pos = atomicAdd(&off[seg], 1);
        sids[pos] = src[e];
    }
}

// ---------------- fused aggregate + MFMA GEMM (pipelined) ----------------
// out[n][j] = bias[j] + feat[n]@root[:,j]
//           + sum_r mean_{e in seg(n,r)} feat[src_e] @ W[r][:,j]
template <int NCOLS, bool RELU, bool OUTBF16>
__global__ __launch_bounds__(256) void fused_gemm_kernel(
    const ushort* __restrict__ feat,   // [N][128] bf16
    const int* __restrict__ sids,      // [E] src ids grouped by (dst*8+et)
    const int* __restrict__ endoff,    // [N*8] end offsets
    const ushort* __restrict__ Wt,     // [R+1][NCOLS][BTSTRIDE] bf16
    const float* __restrict__ bias,    // [NCOLS]
    void* __restrict__ outp,           // [N][NCOLS] bf16 or f32
    int N) {
    constexpr int NT = NCOLS / 16;                    // 16x16 col-tiles/wave
    constexpr int SEGW = NCOLS * BTSTRIDE / 8;        // uint4 per B segment
    __shared__ __align__(16) ushort Bt[2][NCOLS * BTSTRIDE];

    const int tid = threadIdx.x;
    const int wave = tid >> 6;
    const int lane = tid & 63;
    const int c = lane & 15;   // A-row / D-col / B-col within tile
    const int g = lane >> 4;   // k-group
    const int rb = blockIdx.x * 64 + wave * 16;
    const int arow = min(rb + c, N - 1);  // clamped; stores guarded

    // 9 segment boundaries for this row, one coalesced run of endoff
    int so[9];
    {
        int b = arow * NREL;
        so[0] = (b == 0) ? 0 : endoff[b - 1];
#pragma unroll
        for (int s = 1; s <= NREL; ++s) so[s] = endoff[b + s - 1];
    }

    f32x4 acc[NT];
#pragma unroll
    for (int t = 0; t < NT; ++t) acc[t] = (f32x4){0.f, 0.f, 0.f, 0.f};

    const ushort* myrow = feat + (size_t)arow * D_IN + 8 * g;

    // ---- A-fragment builder (registers only, static indexing) ----
    bf16x8 aC[4], aN[4];
#define BUILD_A(S, DST)                                                        \
    do {                                                                       \
        if ((S) < NREL) {                                                      \
            int start = so[(S)], end = so[(S) + 1];                            \
            int deg = end - start;                                             \
            float ac[4][8];                                                    \
            _Pragma("unroll") for (int q = 0; q < 4; ++q)                      \
                _Pragma("unroll") for (int j = 0; j < 8; ++j) ac[q][j] = 0.f;  \
            for (int e = start; e < end; ++e) {                                \
                int id = sids[e];                                              \
                const ushort* row = feat + (size_t)id * D_IN + 8 * g;          \
                _Pragma("unroll") for (int q = 0; q < 4; ++q) {                \
                    uint4 v = *(const uint4*)(row + 32 * q);                   \
                    ac[q][0] += bflo(v.x); ac[q][1] += bfhi(v.x);              \
                    ac[q][2] += bflo(v.y); ac[q][3] += bfhi(v.y);              \
                    ac[q][4] += bflo(v.z); ac[q][5] += bfhi(v.z);              \
                    ac[q][6] += bflo(v.w); ac[q][7] += bfhi(v.w);              \
                }                                                              \
            }                                                                  \
            float inv = (deg > 0) ? 1.0f / (float)deg : 0.0f;                  \
            _Pragma("unroll") for (int q = 0; q < 4; ++q) {                    \
                uint4 pk;                                                      \
                pk.x = (unsigned)cvbf(ac[q][0] * inv) |                        \
                       ((unsigned)cvbf(ac[q][1] * inv) << 16);                 \
                pk.y = (unsigned)cvbf(ac[q][2] * inv) |                        \
                       ((unsigned)cvbf(ac[q][3] * inv) << 16);                 \
                pk.z = (unsigned)cvbf(ac[q][4] * inv) |                        \
                       ((unsigned)cvbf(ac[q][5] * inv) << 16);                 \
                pk.w = (unsigned)cvbf(ac[q][6] * inv) |                        \
                       ((unsigned)cvbf(ac[q][7] * inv) << 16);                 \
                DST[q] = *(bf16x8*)&pk;                                        \
            }                                                                  \
        } else {                                                               \
            _Pragma("unroll") for (int q = 0; q < 4; ++q)                      \
                DST[q] = *(const bf16x8*)(myrow + 32 * q);                     \
        }                                                                      \
    } while (0)

#define STAGE(S, BUF)                                                          \
    do {                                                                       \
        const uint4* srcw = (const uint4*)(Wt + (size_t)(S)*NCOLS * BTSTRIDE); \
        uint4* dstw = (uint4*)(Bt[(BUF)]);                                     \
        for (int i = tid; i < SEGW; i += 256) dstw[i] = srcw[i];               \
    } while (0)

    // prologue
    STAGE(0, 0);
    BUILD_A(0, aC);
    __syncthreads();

    for (int s = 0; s < NREL + 1; ++s) {
        const int cb = s & 1;
        if (s < NREL) {
            STAGE(s + 1, cb ^ 1);   // issue next B staging
            BUILD_A(s + 1, aN);     // issue next A gather (latency hidden)
        }
        const ushort* bt = Bt[cb];
#pragma unroll
        for (int q = 0; q < 4; ++q) {
#pragma unroll
            for (int t = 0; t < NT; ++t) {
                const ushort* bp = bt + (t * 16 + c) * BTSTRIDE + q * 32 + 8 * g;
                bf16x8 b = *(const bf16x8*)bp;
                acc[t] = __builtin_amdgcn_mfma_f32_16x16x32_bf16(aC[q], b, acc[t], 0, 0, 0);
            }
        }
        __syncthreads();  // staging of next buf done; this buf free after s+1
#pragma unroll
        for (int q = 0; q < 4; ++q) aC[q] = aN[q];
    }

    // epilogue: D layout col=lane&15, row=(lane>>4)*4+reg
#pragma unroll
    for (int t = 0; t < NT; ++t) {
        float bv = bias[t * 16 + c];
#pragma unroll
        for (int r = 0; r < 4; ++r) {
            int orow = rb + 4 * g + r;
            if (orow < N) {
                float v = acc[t][r] + bv;
                if (RELU) v = fmaxf(v, 0.0f);
                if (OUTBF16)
                    ((ushort*)outp)[(size_t)orow * NCOLS + t * 16 + c] = cvbf(v);
                else
                    ((float*)outp)[(size_t)orow * NCOLS + t * 16 + c] = v;
            }
        }
    }
#undef BUILD_A
#undef STAGE
}

extern "C" void kernel_launch(void* const* d_in, const int* in_sizes, int n_in,
                              void* d_out, int out_size, void* d_ws, size_t ws_size,
                              hipStream_t stream) {
    const float* x = (const float*)d_in[0];
    const int* ei = (const int*)d_in[1];
    const int* et = (const int*)d_in[2];
    const float* W1 = (const float*)d_in[3];
    const float* root1 = (const float*)d_in[4];
    const float* bias1 = (const float*)d_in[5];
    const float* W2 = (const float*)d_in[6];
    const float* root2 = (const float*)d_in[7];
    const float* bias2 = (const float*)d_in[8];
    float* out = (float*)d_out;

    const int N = in_sizes[0] / D_IN;  // 50000
    const int E = in_sizes[2];         // 800000
    const int* src = ei;
    const int* dst = ei + E;
    const int NSEG = NREL * N;            // 400000
    const int NB = (NSEG + 1023) / 1024;  // 391 (<=512 for scan_bsum)

    // workspace layout (all 16B-aligned)
    ushort* xb = (ushort*)d_ws;                      // N*128 bf16 = 12.8 MB
    ushort* hb = xb + (size_t)N * D_IN;              // N*128 bf16 = 12.8 MB
    ushort* wt1 = hb + (size_t)N * D_IN;             // 9*128*136*2B
    ushort* wt2 = wt1 + (size_t)(NREL + 1) * D_IN * BTSTRIDE;  // 9*64*136*2B
    int* off = (int*)(wt2 + (size_t)(NREL + 1) * 64 * BTSTRIDE);  // NSEG ints
    int* sids = off + NSEG;                          // E ints
    int* cnt = sids + E;                             // NSEG ints
    int* bsum = cnt + NSEG;                          // NB ints

    // ---- input conversions / weight transforms (independent) ----
    to_bf16_kernel<<<(N * D_IN / 4 + 255) / 256, 256, 0, stream>>>(x, xb, N * D_IN / 4);
    wt_transform_kernel<<<((NREL + 1) * D_IN * 128 + 255) / 256, 256, 0, stream>>>(
        W1, root1, wt1, 128);
    wt_transform_kernel<<<((NREL + 1) * D_IN * 64 + 255) / 256, 256, 0, stream>>>(
        W2, root2, wt2, 64);

    // ---- CSR build (edge set identical for both layers) ----
    hipMemsetAsync(cnt, 0, (size_t)NSEG * sizeof(int), stream);
    count_kernel<<<(E + 255) / 256, 256, 0, stream>>>(dst, et, cnt, E, N);
    scan_block_sum<<<NB, 256, 0, stream>>>(cnt, bsum, NSEG);
    scan_bsum<<<1, 512, 0, stream>>>(bsum, NB);
    scan_write<<<NB, 256, 0, stream>>>(cnt, bsum, off, NSEG);
    bucket_kernel<<<(E + 255) / 256, 256, 0, stream>>>(src, dst, et, off, sids, E, N);
    // off[] now holds END offsets per segment.

    const int gemmBlocks = (N + 63) / 64;

    // ---- layer 1 (fused aggregate+GEMM) ----
    fused_gemm_kernel<128, true, true><<<gemmBlocks, 256, 0, stream>>>(
        xb, sids, off, wt1, bias1, hb, N);

    // ---- layer 2 ----
    fused_gemm_kernel<64, false, false><<<gemmBlocks, 256, 0, stream>>>(
        hb, sids, off, wt2, bias2, out, N);
}